// Round 4
// baseline (1323.680 us; speedup 1.0000x reference)
//
#include <hip/hip_runtime.h>
#include <math.h>

// KAN activation: out = wb * silu(x) + ws * BSpline(knots, coeffs, k=3)(x)
//
// Round 4 = discriminating experiment:
//   dispatch 1: pure float4 copy probe x->out (m13 pattern) — measures the
//               achievable stream BW of THIS rig/harness, per-dispatch in
//               rocprof.
//   dispatch 2: KAN kernel, register software-pipelined (next float4 loaded
//               before current eval chain), overwrites out so the final
//               result is correct.
// Decision rule in journal: copy fast + kan fast = win; copy fast + kan
// slow = kernel structure; copy slow = environment throttle (roofline).

typedef float f4 __attribute__((ext_vector_type(4)));

__global__ __launch_bounds__(256) void copy_probe(const f4* __restrict__ in,
                                                  f4* __restrict__ out,
                                                  unsigned n4)
{
    unsigned i = blockIdx.x * 256u + threadIdx.x;
    const unsigned stride = gridDim.x * 256u;
    for (; i < n4; i += stride) out[i] = in[i];
}

__global__ __launch_bounds__(256) void kan_kernel(
    const float* __restrict__ xin,
    const float* __restrict__ knots,
    const float* __restrict__ coeffs,
    const float* __restrict__ wbp,
    const float* __restrict__ wsp,
    float* __restrict__ out,
    unsigned n4)
{
    // ---- uniform preloads ----
    const float t1 = knots[1], t2 = knots[2], t3 = knots[3], t4 = knots[4];
    const float t5 = knots[5], t6 = knots[6], t7 = knots[7], t8 = knots[8];
    const float c0 = coeffs[0], c1 = coeffs[1], c2 = coeffs[2];
    const float c3 = coeffs[3], c4 = coeffs[4], c5 = coeffs[5];
    const float wb = wbp[0], ws = wsp[0];

    // 12 inverse denominators hoisted (exact div once per thread).
    const float inv3_1 = 1.0f / (t4 - t1), inv3_2 = 1.0f / (t5 - t2);
    const float inv3_3 = 1.0f / (t6 - t3), inv3_4 = 1.0f / (t7 - t4);
    const float inv3_5 = 1.0f / (t8 - t5);
    const float inv2_2 = 1.0f / (t4 - t2), inv2_3 = 1.0f / (t5 - t3);
    const float inv2_4 = 1.0f / (t6 - t4), inv2_5 = 1.0f / (t7 - t5);
    const float inv1_3 = 1.0f / (t4 - t3), inv1_4 = 1.0f / (t5 - t4);
    const float inv1_5 = 1.0f / (t6 - t5);

    auto eval = [&](float x) -> float {
        const bool ge4 = (x >= t4);
        const bool ge5 = (x >= t5);
#define KAN_SEL(a, b, c) (ge4 ? (ge5 ? (c) : (b)) : (a))
        float d0 = KAN_SEL(c0, c1, c2);
        float d1 = KAN_SEL(c1, c2, c3);
        float d2 = KAN_SEL(c2, c3, c4);
        float d3 = KAN_SEL(c3, c4, c5);
        const float ti   = KAN_SEL(t3, t4, t5);
        const float tim1 = KAN_SEL(t2, t3, t4);
        const float tim2 = KAN_SEL(t1, t2, t3);
        const float i13 = KAN_SEL(inv3_3, inv3_4, inv3_5);
        const float i12 = KAN_SEL(inv3_2, inv3_3, inv3_4);
        const float i11 = KAN_SEL(inv3_1, inv3_2, inv3_3);
        const float i23 = KAN_SEL(inv2_3, inv2_4, inv2_5);
        const float i22 = KAN_SEL(inv2_2, inv2_3, inv2_4);
        const float i33 = KAN_SEL(inv1_3, inv1_4, inv1_5);
#undef KAN_SEL
        const float u0 = x - ti;
        const float u1 = x - tim1;
        const float u2 = x - tim2;
        float a;
        a = u0 * i13; d3 = fmaf(a, d3 - d2, d2);
        a = u1 * i12; d2 = fmaf(a, d2 - d1, d1);
        a = u2 * i11; d1 = fmaf(a, d1 - d0, d0);
        a = u0 * i23; d3 = fmaf(a, d3 - d2, d2);
        a = u1 * i22; d2 = fmaf(a, d2 - d1, d1);
        a = u0 * i33; d3 = fmaf(a, d3 - d2, d2);
        const float e = __expf(-x);
        const float b = x * __builtin_amdgcn_rcpf(1.0f + e);
        return fmaf(wb, b, ws * d3);
    };

    const f4* __restrict__ x4 = (const f4*)xin;
    f4* __restrict__ o4 = (f4*)out;

    unsigned i = blockIdx.x * 256u + threadIdx.x;
    const unsigned stride = gridDim.x * 256u;
    if (i >= n4) return;

    // Software pipeline: next iteration's load is unconditional (clamped
    // index) and independent of the current eval chain, so it issues before
    // the ~300-cycle compute and each wave always has a load in flight.
    f4 cur = x4[i];
    while (true) {
        const unsigned nx = i + stride;
        const bool has = nx < n4;
        const f4 nxt = x4[has ? nx : i];  // clamped: always a valid address
        f4 ov;
        ov.x = eval(cur.x);
        ov.y = eval(cur.y);
        ov.z = eval(cur.z);
        ov.w = eval(cur.w);
        o4[i] = ov;
        if (!has) break;
        i = nx;
        cur = nxt;
    }
}

__global__ void kan_tail(const float* __restrict__ xin,
                         const float* __restrict__ knots,
                         const float* __restrict__ coeffs,
                         const float* __restrict__ wbp,
                         const float* __restrict__ wsp,
                         float* __restrict__ out,
                         unsigned start, unsigned n)
{
    const unsigned j = start + blockIdx.x * blockDim.x + threadIdx.x;
    if (j >= n) return;
    const float x = xin[j];
    float t[10], c[6];
    for (int q = 0; q < 10; ++q) t[q] = knots[q];
    for (int q = 0; q < 6; ++q) c[q] = coeffs[q];
    int i = 3 + (x >= t[4] ? 1 : 0) + (x >= t[5] ? 1 : 0);
    float d[4];
    for (int q = 0; q <= 3; ++q) d[q] = c[i - 3 + q];
    for (int r = 1; r <= 3; ++r)
        for (int q = 3; q >= r; --q) {
            const float tlo = t[i + q - 3], thi = t[i + q + 1 - r];
            const float al = (x - tlo) / (thi - tlo);
            d[q] = (1.0f - al) * d[q - 1] + al * d[q];
        }
    const float b = x / (1.0f + __expf(-x));
    out[j] = wbp[0] * b + wsp[0] * d[3];
}

extern "C" void kernel_launch(void* const* d_in, const int* in_sizes, int n_in,
                              void* d_out, int out_size, void* d_ws, size_t ws_size,
                              hipStream_t stream) {
    const float* x      = (const float*)d_in[0];
    const float* knots  = (const float*)d_in[1];
    const float* coeffs = (const float*)d_in[2];
    const float* wb     = (const float*)d_in[3];
    const float* ws     = (const float*)d_in[4];
    float* out = (float*)d_out;

    const unsigned n  = (unsigned)out_size;
    const unsigned n4 = n >> 2;
    const int block = 256;
    const int grid  = 2048;  // 8 blocks/CU, grid-stride (16 iters at n=2^25)

    // Dispatch 1: BW probe (result overwritten by dispatch 2; final output
    // is correct and deterministic).
    copy_probe<<<grid, block, 0, stream>>>((const f4*)x, (f4*)out, n4);
    // Dispatch 2: the real kernel.
    kan_kernel<<<grid, block, 0, stream>>>(x, knots, coeffs, wb, ws, out, n4);

    const unsigned rem = n & 3u;
    if (rem) {
        kan_tail<<<1, 64, 0, stream>>>(x, knots, coeffs, wb, ws, out, n - rem, n);
    }
}

// Round 5
// 52.116 us; speedup vs baseline: 25.3985x; 25.3985x over previous
//
#include <hip/hip_runtime.h>
#include <math.h>

// KAN activation: out = wb * silu(x) + ws * BSpline(knots, coeffs, k=3)(x)
//
// Round 5 structure ("collapse the uniforms"):
//   The spline has only 3 reachable intervals (i = clip(searchsorted-1,3,5)),
//   and on each interval it is a plain cubic. So:
//   - kan_setup (1 thread, fp64): exact de Boor at 4 nodes per interval ->
//     Newton divided differences -> monomial coeffs in local coord u=x-t[i].
//     Writes 17 floats to d_ws: 3x float4 poly + t3,t4,t5 + wb + ws.
//   - kan_main: stages those 17 floats to LDS once per block; per element:
//     2 compares -> ds_read_b128 of the interval's float4 -> Horner(3 fma)
//     -> silu -> blend. Live uniform state: 5 floats. No divisions, no
//     28-scalar uniform set to spill (r1-r4 post-mortem: VGPR=32 with ~28
//     live uniforms -> per-iteration remat/spill traffic, FETCH 2.4-4.4 GB).

typedef float f4 __attribute__((ext_vector_type(4)));

__global__ void kan_setup(const float* __restrict__ knots,
                          const float* __restrict__ coeffs,
                          const float* __restrict__ wbp,
                          const float* __restrict__ wsp,
                          float* __restrict__ wsbuf)
{
    if (blockIdx.x != 0 || threadIdx.x != 0) return;

    double t[10], c[6];
    #pragma unroll
    for (int q = 0; q < 10; ++q) t[q] = (double)knots[q];
    #pragma unroll
    for (int q = 0; q < 6; ++q)  c[q] = (double)coeffs[q];

    #pragma unroll
    for (int m = 0; m < 3; ++m) {
        const int i = m + 3;
        const double h = t[i + 1] - t[i];
        double S[4], U[4];
        #pragma unroll
        for (int j = 0; j < 4; ++j) {
            const double u = h * (double)j * (1.0 / 3.0);
            U[j] = u;
            const double x = t[i] + u;
            // de Boor with FIXED interval i (matches reference incl. the
            // clipped/extrapolation pieces, which use the boundary poly).
            double d0 = c[i - 3], d1 = c[i - 2], d2 = c[i - 1], d3 = c[i];
            double a;
            a = (x - t[i])     / (t[i + 3] - t[i]);     d3 = (1.0 - a) * d2 + a * d3;
            a = (x - t[i - 1]) / (t[i + 2] - t[i - 1]); d2 = (1.0 - a) * d1 + a * d2;
            a = (x - t[i - 2]) / (t[i + 1] - t[i - 2]); d1 = (1.0 - a) * d0 + a * d1;
            a = (x - t[i])     / (t[i + 2] - t[i]);     d3 = (1.0 - a) * d2 + a * d3;
            a = (x - t[i - 1]) / (t[i + 1] - t[i - 1]); d2 = (1.0 - a) * d1 + a * d2;
            a = (x - t[i])     / (t[i + 1] - t[i]);     d3 = (1.0 - a) * d2 + a * d3;
            S[j] = d3;
        }
        // Newton divided differences on (U, S); U[0] = 0.
        const double dd01 = (S[1] - S[0]) / (U[1] - U[0]);
        const double dd11 = (S[2] - S[1]) / (U[2] - U[1]);
        const double dd21 = (S[3] - S[2]) / (U[3] - U[2]);
        const double dd02 = (dd11 - dd01) / (U[2] - U[0]);
        const double dd12 = (dd21 - dd11) / (U[3] - U[1]);
        const double dd03 = (dd12 - dd02) / (U[3] - U[0]);
        // Monomial expansion in u (U[0]=0):
        const double c3 = dd03;
        const double c2 = dd02 - dd03 * (U[1] + U[2]);
        const double c1 = dd01 - dd02 * U[1] + dd03 * (U[1] * U[2]);
        const double c0 = S[0];
        wsbuf[m * 4 + 0] = (float)c0;
        wsbuf[m * 4 + 1] = (float)c1;
        wsbuf[m * 4 + 2] = (float)c2;
        wsbuf[m * 4 + 3] = (float)c3;
    }
    wsbuf[12] = knots[3];
    wsbuf[13] = knots[4];
    wsbuf[14] = knots[5];
    wsbuf[15] = wbp[0];
    wsbuf[16] = wsp[0];
}

__global__ __launch_bounds__(256) void kan_main(
    const f4* __restrict__ x4,
    const float* __restrict__ wsbuf,
    f4* __restrict__ o4,
    unsigned n4)
{
    __shared__ __attribute__((aligned(16))) float lds[20];
    if (threadIdx.x < 17) lds[threadIdx.x] = wsbuf[threadIdx.x];
    __syncthreads();

    const float t3 = lds[12], t4 = lds[13], t5 = lds[14];
    const float wb = lds[15], wsc = lds[16];

    unsigned i = blockIdx.x * 256u + threadIdx.x;
    const unsigned stride = gridDim.x * 256u;
    for (; i < n4; i += stride) {
        const f4 xv = x4[i];
        f4 ov;
        #pragma unroll
        for (int q = 0; q < 4; ++q) {
            const float x = xv[q];
            const bool ge4 = (x >= t4);
            const bool ge5 = (x >= t5);
            const unsigned off = (ge4 ? 4u : 0u) + (ge5 ? 4u : 0u);
            const f4 pc = *(const f4*)&lds[off];           // ds_read_b128, <=3 addrs
            const float tref = ge4 ? (ge5 ? t5 : t4) : t3;
            const float u = x - tref;
            float s = fmaf(fmaf(fmaf(pc.w, u, pc.z), u, pc.y), u, pc.x);
            const float e = __expf(-x);
            const float b = x * __builtin_amdgcn_rcpf(1.0f + e);
            ov[q] = fmaf(wb, b, wsc * s);
        }
        o4[i] = ov;
    }
}

__global__ void kan_tail(const float* __restrict__ xin,
                         const float* __restrict__ wsbuf,
                         float* __restrict__ out,
                         unsigned start, unsigned n)
{
    const unsigned j = start + blockIdx.x * blockDim.x + threadIdx.x;
    if (j >= n) return;
    const float x = xin[j];
    const float t3 = wsbuf[12], t4 = wsbuf[13], t5 = wsbuf[14];
    const bool ge4 = (x >= t4), ge5 = (x >= t5);
    const int m = (ge4 ? 1 : 0) + (ge5 ? 1 : 0);
    const float tref = ge4 ? (ge5 ? t5 : t4) : t3;
    const float u = x - tref;
    const float p0 = wsbuf[m * 4 + 0], p1 = wsbuf[m * 4 + 1];
    const float p2 = wsbuf[m * 4 + 2], p3 = wsbuf[m * 4 + 3];
    const float s = fmaf(fmaf(fmaf(p3, u, p2), u, p1), u, p0);
    const float b = x / (1.0f + __expf(-x));
    out[j] = fmaf(wsbuf[15], b, wsbuf[16] * s);
}

extern "C" void kernel_launch(void* const* d_in, const int* in_sizes, int n_in,
                              void* d_out, int out_size, void* d_ws, size_t ws_size,
                              hipStream_t stream) {
    const float* x      = (const float*)d_in[0];
    const float* knots  = (const float*)d_in[1];
    const float* coeffs = (const float*)d_in[2];
    const float* wb     = (const float*)d_in[3];
    const float* ws     = (const float*)d_in[4];
    float* out   = (float*)d_out;
    float* wsbuf = (float*)d_ws;   // 17 floats used

    const unsigned n  = (unsigned)out_size;
    const unsigned n4 = n >> 2;

    kan_setup<<<1, 64, 0, stream>>>(knots, coeffs, wb, ws, wsbuf);
    kan_main<<<2048, 256, 0, stream>>>((const f4*)x, wsbuf, (f4*)out, n4);

    const unsigned rem = n & 3u;
    if (rem) {
        kan_tail<<<1, 64, 0, stream>>>(x, wsbuf, out, n - rem, n);
    }
}